// Round 13
// baseline (579.804 us; speedup 1.0000x reference)
//
#include <hip/hip_runtime.h>
#include <hip/hip_bf16.h>

#define BB   16
#define CCH  256
#define DQK  32
#define NTOK 4096

typedef __attribute__((ext_vector_type(8)))  short short8;
typedef __attribute__((ext_vector_type(8)))  int   i32x8;
typedef __attribute__((ext_vector_type(4)))  float f32x4;
typedef __attribute__((ext_vector_type(16))) float f32x16;
typedef unsigned short u16t;
typedef unsigned int   u32t;
typedef long long      i64t;

__device__ __forceinline__ u16t f2bf(float f){
  u32t u = __builtin_bit_cast(u32t, f);
  u += 0x7FFFu + ((u >> 16) & 1u);
  return (u16t)(u >> 16);
}
__device__ __forceinline__ u32t pk2(float a, float b){
  return (u32t)f2bf(a) | ((u32t)f2bf(b) << 16);
}
__device__ __forceinline__ void lane32swap(u32t& a, u32t& b){
  asm("v_permlane32_swap_b32 %0, %1" : "+v"(a), "+v"(b));
}
__device__ __forceinline__ float swapadd(float x){
  u32t a = __builtin_bit_cast(u32t, x), b = a;
  lane32swap(a, b);
  return __builtin_bit_cast(float, a) + __builtin_bit_cast(float, b);
}
__device__ __forceinline__ void gload16(const void* g, void* l){
  __builtin_amdgcn_global_load_lds(
      (const __attribute__((address_space(1))) void*)g,
      (__attribute__((address_space(3))) void*)l, 16, 0, 0);
}
__device__ __forceinline__ f32x16 zero16(){
  f32x16 z;
  #pragma unroll
  for (int i = 0; i < 16; ++i) z[i] = 0.f;
  return z;
}
#define mfma32(A, B, C)  __builtin_amdgcn_mfma_f32_32x32x16_bf16((A), (B), (C), 0, 0, 0)
// MX-scale fp8 K=64 PV MFMA; scales = 127 (e8m0 => 2^0), FMT 0 = e4m3
#define mfmaMX(A, B, C)  __builtin_amdgcn_mfma_scale_f32_32x32x64_f8f6f4((A), (B), (C), 0, 0, 0, 127, 0, 127)
__device__ __forceinline__ u32t pack4fp8(float a, float b, float c, float d){
  int t = __builtin_amdgcn_cvt_pk_fp8_f32(a, b, 0, false);
  t = __builtin_amdgcn_cvt_pk_fp8_f32(c, d, t, true);
  return (u32t)t;
}
__device__ __forceinline__ unsigned char tofp8(float v){
  return (unsigned char)(__builtin_amdgcn_cvt_pk_fp8_f32(v, 0.f, 0, false) & 0xFF);
}

// ---------------- Kernel W: convert Wq|Wk|Wv f32 -> bf16 into d_out scratch ----
__global__ __launch_bounds__(256) void k_wconv(const float* __restrict__ Wq,
    const float* __restrict__ Wk, const float* __restrict__ Wv,
    u16t* __restrict__ o){
  const int base = (blockIdx.x * 256 + threadIdx.x) * 4;   // 81920 total elems
  float4 v;
  if (base < 8192)        v = *(const float4*)(Wq + base);
  else if (base < 16384)  v = *(const float4*)(Wk + base - 8192);
  else                    v = *(const float4*)(Wv + base - 16384);
  *(uint2*)(o + base) = make_uint2(pk2(v.x, v.y), pk2(v.z, v.w));
}

// ---------------- Kernel 1: fused transpose + projections ----------------
// Q,K bf16 [B][N][32] (Q pre-scaled by log2e). V fp8 e4m3 [B][C][4096] with
// per-row 8B-group swizzle baked in at WRITE time (rule #21).
__global__ __launch_bounds__(256) void k_proj(const float* __restrict__ x,
    const u16t* __restrict__ Wb,
    const float* __restrict__ bq, const float* __restrict__ bk,
    const float* __restrict__ bv,
    u16t* __restrict__ Q, u16t* __restrict__ K, unsigned char* __restrict__ V){
  __shared__ __align__(16) u16t xt[32 * 512];   // 32 chunks x 1KB
  const int b = blockIdx.y, nb = blockIdx.x * 64;
  const int tid = threadIdx.x;
  const int w = tid >> 6, lane = tid & 63;
  const int lo = lane & 15, g = lane >> 4;

  // ---- stage x tile (fragment-order scatter) ----
  const float* xb = x + (size_t)b * CCH * NTOK + nb;
  const int cg = tid >> 4, n0 = (tid & 15) * 4;
  #pragma unroll
  for (int rep = 0; rep < 16; ++rep){
    const int c = rep * 16 + cg;
    float4 v = *(const float4*)(xb + (size_t)c * NTOK + n0);
    const int chunkb = (n0 >> 4) * 8 + (c >> 5);
    const int fl = 16 * ((c >> 3) & 3);
    const int e = c & 7;
    xt[chunkb * 512 + ((n0 & 15) + 0 + fl) * 8 + e] = f2bf(v.x);
    xt[chunkb * 512 + ((n0 & 15) + 1 + fl) * 8 + e] = f2bf(v.y);
    xt[chunkb * 512 + ((n0 & 15) + 2 + fl) * 8 + e] = f2bf(v.z);
    xt[chunkb * 512 + ((n0 & 15) + 3 + fl) * 8 + e] = f2bf(v.w);
  }
  __syncthreads();

  #pragma unroll
  for (int ot = 0; ot < 5; ++ot){
    const u16t* Wrow; const float* bias; int ob; int mode;
    if (ot == 0){
      if (w < 2){ Wrow = Wb;        bias = bq; ob = w * 16;       mode = 0; }
      else      { Wrow = Wb + 8192; bias = bk; ob = (w - 2) * 16; mode = 1; }
    } else { Wrow = Wb + 16384; bias = bv; ob = (ot - 1) * 64 + w * 16; mode = 2; }
    const u16t* wp = Wrow + (size_t)(ob + lo) * CCH + g * 8;

    f32x4 acc[4];
    #pragma unroll
    for (int s = 0; s < 4; ++s) acc[s] = (f32x4){0.f, 0.f, 0.f, 0.f};
    #pragma unroll
    for (int kc = 0; kc < CCH; kc += 32){
      const short8 af = *(const short8*)(wp + kc);
      #pragma unroll
      for (int s = 0; s < 4; ++s){
        const short8 bf = *(const short8*)(xt + (s * 8 + (kc >> 5)) * 512 + lane * 8);
        acc[s] = __builtin_amdgcn_mfma_f32_16x16x32_bf16(af, bf, acc[s], 0, 0, 0);
      }
    }
    #pragma unroll
    for (int s = 0; s < 4; ++s){
      #pragma unroll
      for (int r = 0; r < 4; ++r){
        const int o = ob + 4 * g + r;
        const int n = nb + s * 16 + lo;
        float val = acc[s][r] + bias[o];
        if (mode == 0){
          val *= 1.44269504088896f;
          Q[((size_t)b * NTOK + n) * DQK + o] = f2bf(val);
        } else if (mode == 1){
          K[((size_t)b * NTOK + n) * DQK + o] = f2bf(val);
        } else {
          // fp8 V with baked swizzle: group = (n&63)>>3, slot = group ^ ((o>>1)&7)
          const int swz = ((((s * 2) + (lo >> 3)) ^ ((o >> 1) & 7)) << 3) + (lo & 7);
          V[((size_t)b * CCH + o) * (size_t)NTOK + nb + swz] = tofp8(val);
        }
      }
    }
  }
}

// ---------------- Kernel 2: flash attention + epilogue ----------------
// grid 512, block 512 (8 waves = 4 q-groups x 2 ch-halves), 2 blocks/CU ->
// 4 waves/SIMD. P-sharing by j-half (R12) + PV via MX-scale fp8 K=64 MFMA:
// 4 mfma_scale_32x32x64 per wave-iter (vs 16 32x32x16) -> matrix pipe ~halved.
// P-LDS layout [qg][jq 0..15][q]*4B: producer 4x b32 writes (banks=ql, free),
// consumer 8x b32 reads (fusable ds_read2), no permlane needed. Static-m
// softmax (P=exp2(S) raw), partial-l combined in epilogue.
__global__ __launch_bounds__(512, 4) void k_attn(
    const u16t* __restrict__ Q, const u16t* __restrict__ K,
    const unsigned char* __restrict__ V,
    const float* __restrict__ x, const float* __restrict__ gamma,
    float* __restrict__ out){
  __shared__ __align__(16) u16t KT[2 * 2048];             // 8 KB K dbuf
  __shared__ __align__(16) unsigned char Vt[2][16384];    // 32 KB V dbuf fp8
  __shared__ __align__(16) unsigned char PT[2][8192];     // 16 KB P dbuf fp8
  const int bid = blockIdx.x;
  const int b  = ((bid & 7) << 1) | ((bid >> 3) & 1);
  const int qt = bid >> 4;
  const int tid = threadIdx.x, w = tid >> 6, lane = tid & 63;
  const int qg = w & 3, ch = w >> 2;
  const int ql = lane & 31, hi = lane >> 5;
  const int qgb = qt * 128 + qg * 32;

  const u16t* Qb = Q + (size_t)b * NTOK * DQK;
  const u16t* Kb = K + (size_t)b * NTOK * DQK;
  const unsigned char* Vb = V + (size_t)b * CCH * NTOK;

  const short8 qf0 = *(const short8*)(Qb + (size_t)(qgb + ql) * DQK + hi * 8);
  const short8 qf1 = *(const short8*)(Qb + (size_t)(qgb + ql) * DQK + 16 + hi * 8);

  f32x16 acc[4];                      // 128 channels -> 64 f32
  #pragma unroll
  for (int c = 0; c < 4; ++c) acc[c] = zero16();
  float l = 0.f;

  // ---- precomputed addresses ----
  // V staging: wave stages bytes [w*2048, w*2048+2048): row = a>>6, col16 = lane&3
  const char* vsrc0 = (const char*)Vb + (size_t)(w * 32 + (lane >> 2)) * NTOK + (lane & 3) * 16;
  // K staging (waves 0..3), fragment order
  const size_t kse = (size_t)((w & 1) * 32 + ql) * DQK + (w >> 1) * 16 + hi * 8;
  const char* ksrc0 = (const char*)Kb + kse * 2;
  const int kla = lane * 16;
  // V A-fragment (K=64): lane (ql,hi) reads j groups g=4hi+i, i=0..3 of row
  // c = ch*128 + cs*32 + ql; slot = g ^ ((c>>1)&7) -- (c>>1)&7 is cs-invariant.
  int va[4];
  #pragma unroll
  for (int i = 0; i < 4; ++i){
    const int c0 = ch * 128 + ql;
    va[i] = (c0 & 127) * 64 + ch * 8192 + (((4 * hi + i) ^ ((c0 >> 1) & 7)) << 3);
  }
  const char* ldsV = (const char*)&Vt[0][0];
  const char* ldsK = (const char*)&KT[0];
  const char* ldsP = (const char*)&PT[0][0];
  // producer P write base: [qg][jq = ch*8 + w*2 + hi][q=ql]
  char* ldsPw = (char*)&PT[0][0] + qg * 2048 + ch * 1024 + hi * 128 + ql * 4;
  // consumer P read base: [qg][jq = hi*8 + i][q=ql]
  const int pread = qg * 2048 + hi * 1024 + ql * 4;

  #define ESL(S, B) \
    { S[(B)+0] = __builtin_amdgcn_exp2f(S[(B)+0]); r0 += S[(B)+0]; \
      S[(B)+1] = __builtin_amdgcn_exp2f(S[(B)+1]); r1 += S[(B)+1]; \
      S[(B)+2] = __builtin_amdgcn_exp2f(S[(B)+2]); r2 += S[(B)+2]; \
      S[(B)+3] = __builtin_amdgcn_exp2f(S[(B)+3]); r3 += S[(B)+3]; }

  #define PVCHUNK(CS, VRD, EXPSLICE) \
    { const uint2 v0 = *(const uint2*)(ldsV + va[0] + (VRD)*16384 + (CS)*2048); \
      const uint2 v1 = *(const uint2*)(ldsV + va[1] + (VRD)*16384 + (CS)*2048); \
      const uint2 v2 = *(const uint2*)(ldsV + va[2] + (VRD)*16384 + (CS)*2048); \
      const uint2 v3 = *(const uint2*)(ldsV + va[3] + (VRD)*16384 + (CS)*2048); \
      i32x8 av; \
      av[0] = (int)v0.x; av[1] = (int)v0.y; av[2] = (int)v1.x; av[3] = (int)v1.y; \
      av[4] = (int)v2.x; av[5] = (int)v2.y; av[6] = (int)v3.x; av[7] = (int)v3.y; \
      acc[CS] = mfmaMX(av, pbv, acc[CS]); \
      EXPSLICE \
      __builtin_amdgcn_sched_group_barrier(0x100, 4, 0); \
      __builtin_amdgcn_sched_group_barrier(0x8,   1, 0); \
      __builtin_amdgcn_sched_group_barrier(0x2,   8, 0); }

  #define NOSL
  // read P fragment (8 b32, jq = hi*8 + i) from PT[VRD]
  #define PBREADS(VRD) \
      i32x8 pbv; \
      _Pragma("unroll") \
      for (int i_ = 0; i_ < 8; ++i_) \
        pbv[i_] = *(const int*)(ldsP + (VRD)*8192 + pread + i_*128);

  // QK for own j-half from K slot KRD
  #define QKH(KRD, S) \
      { const char* kb_ = ldsK + (KRD)*4096 + ch*1024 + kla; \
        const short8 kfA = *(const short8*)(kb_); \
        const short8 kfB = *(const short8*)(kb_ + 2048); \
        S = mfma32(kfA, qf0, zero16()); \
        S = mfma32(kfB, qf1, S); }

  // pack 16 exp'd scores -> 4 b32 words at jq = w*2+hi (offsets w*256)
  #define PWRITE(S, WB) \
      { *(u32t*)(ldsPw + (WB)*8192 +   0) = pack4fp8(S[0],  S[1],  S[2],  S[3]); \
        *(u32t*)(ldsPw + (WB)*8192 + 256) = pack4fp8(S[4],  S[5],  S[6],  S[7]); \
        *(u32t*)(ldsPw + (WB)*8192 + 512) = pack4fp8(S[8],  S[9],  S[10], S[11]); \
        *(u32t*)(ldsPw + (WB)*8192 + 768) = pack4fp8(S[12], S[13], S[14], S[15]); }

  #define ABODY(T, VRD, KRD, KST) { \
      const int toff_ = ((T) + 1) * 64; \
      gload16(vsrc0 + toff_,                     &Vt[(VRD)^1][w * 2048]); \
      gload16(vsrc0 + (size_t)16 * NTOK + toff_, &Vt[(VRD)^1][w * 2048 + 1024]); \
      if (w < 4){ const int kt2_ = ((T) + 2 <= 63) ? (T) + 2 : 63; \
        gload16(ksrc0 + (size_t)kt2_ * 4096, &KT[(KST) * 2048 + w * 512]); } \
      PBREADS(VRD) \
      f32x16 s; \
      QKH(KRD, s) \
      float r0 = 0.f, r1 = 0.f, r2 = 0.f, r3 = 0.f; \
      PVCHUNK(0, VRD, ESL(s, 0)) \
      PVCHUNK(1, VRD, ESL(s, 4)) \
      PVCHUNK(2, VRD, ESL(s, 8)) \
      PVCHUNK(3, VRD, ESL(s, 12)) \
      l += (r0 + r1) + (r2 + r3); \
      PWRITE(s, (VRD)^1) \
      __syncthreads(); }

  // prologue: stage V(0)->buf0, K(0)->slot0, K(1)->slot1
  gload16(vsrc0,                     &Vt[0][w * 2048]);
  gload16(vsrc0 + (size_t)16 * NTOK, &Vt[0][w * 2048 + 1024]);
  if (w < 4){
    gload16(ksrc0,        &KT[0 * 2048 + w * 512]);
    gload16(ksrc0 + 4096, &KT[1 * 2048 + w * 512]);
  }
  __syncthreads();

  // prologue compute: P(0) for own j-half -> PT[0]
  {
    f32x16 s;
    QKH(0, s)
    float r0 = 0.f, r1 = 0.f, r2 = 0.f, r3 = 0.f;
    ESL(s, 0) ESL(s, 4) ESL(s, 8) ESL(s, 12)
    l = (r0 + r1) + (r2 + r3);
    PWRITE(s, 0)
  }
  __syncthreads();   // P(0) visible; K slot0 safe to overwrite in t=0

  for (int t = 0; t < 62; t += 2){
    ABODY(t,     0, 1, 0)
    ABODY(t + 1, 1, 0, 1)
  }
  ABODY(62, 0, 1, 0)

  // tail: PV(63) from Vt[1] / PT[1]
  {
    PBREADS(1)
    PVCHUNK(0, 1, NOSL) PVCHUNK(1, 1, NOSL)
    PVCHUNK(2, 1, NOSL) PVCHUNK(3, 1, NOSL)
  }

  // ---- epilogue: combine l halves, out = gamma * O/l + x ----
  __syncthreads();                         // all PT[1] reads done
  const float lhalf = swapadd(l);          // full sum over own j-half
  float* lx = (float*)&PT[0][0];
  if (lane < 32) lx[(qg * 2 + ch) * 32 + ql] = lhalf;
  __syncthreads();
  const float lfull = lhalf + lx[(qg * 2 + (ch ^ 1)) * 32 + ql];
  const float inv = 1.0f / lfull;
  const float gm = gamma[0];
  const int n = qgb + ql;
  #pragma unroll
  for (int cs = 0; cs < 4; ++cs){
    #pragma unroll
    for (int r = 0; r < 16; ++r){
      const int c = ch * 128 + cs * 32 + (r & 3) + 8 * (r >> 2) + 4 * hi;
      const size_t idx = ((size_t)b * CCH + c) * NTOK + n;
      out[idx] = gm * (acc[cs][r] * inv) + x[idx];
    }
  }
  #undef ESL
  #undef PVCHUNK
  #undef NOSL
  #undef PBREADS
  #undef QKH
  #undef PWRITE
  #undef ABODY
}

extern "C" void kernel_launch(void* const* d_in, const int* in_sizes, int n_in,
                              void* d_out, int out_size, void* d_ws, size_t ws_size,
                              hipStream_t stream) {
  const float* x     = (const float*)d_in[0];
  const float* Wq    = (const float*)d_in[1];
  const float* bq    = (const float*)d_in[2];
  const float* Wk    = (const float*)d_in[3];
  const float* bk    = (const float*)d_in[4];
  const float* Wv    = (const float*)d_in[5];
  const float* bv    = (const float*)d_in[6];
  const float* gamma = (const float*)d_in[7];
  float* out = (float*)d_out;

  char* ws = (char*)d_ws;
  u16t* Qw = (u16t*)(ws);                      //  4 MB
  u16t* Kw = (u16t*)(ws + 4194304);            //  4 MB
  unsigned char* Vw = (unsigned char*)(ws + 8388608);  // 16 MB fp8
  u16t* Wbf = (u16t*)d_out;                    // 160 KB scratch, overwritten by k_attn

  hipLaunchKernelGGL(k_wconv, dim3(80), dim3(256), 0, stream, Wq, Wk, Wv, Wbf);
  hipLaunchKernelGGL(k_proj, dim3(NTOK / 64, BB), dim3(256), 0, stream,
                     x, Wbf, bq, bk, bv, Qw, Kw, Vw);
  hipLaunchKernelGGL(k_attn, dim3(512), dim3(512), 0, stream,
                     Qw, Kw, Vw, x, gamma, out);
}

// Round 15
// 413.217 us; speedup vs baseline: 1.4031x; 1.4031x over previous
//
#include <hip/hip_runtime.h>
#include <hip/hip_bf16.h>

#define BB   16
#define CCH  256
#define DQK  32
#define NTOK 4096

typedef __attribute__((ext_vector_type(8)))  short short8;
typedef __attribute__((ext_vector_type(4)))  float f32x4;
typedef __attribute__((ext_vector_type(16))) float f32x16;
typedef unsigned short u16t;
typedef unsigned int   u32t;
typedef long long      i64t;

__device__ __forceinline__ u16t f2bf(float f){
  u32t u = __builtin_bit_cast(u32t, f);
  u += 0x7FFFu + ((u >> 16) & 1u);
  return (u16t)(u >> 16);
}
__device__ __forceinline__ u32t pk2(float a, float b){
  return (u32t)f2bf(a) | ((u32t)f2bf(b) << 16);
}
__device__ __forceinline__ void lane32swap(u32t& a, u32t& b){
  asm("v_permlane32_swap_b32 %0, %1" : "+v"(a), "+v"(b));
}
__device__ __forceinline__ float swapadd(float x){
  u32t a = __builtin_bit_cast(u32t, x), b = a;
  lane32swap(a, b);
  return __builtin_bit_cast(float, a) + __builtin_bit_cast(float, b);
}
__device__ __forceinline__ void gload16(const void* g, void* l){
  __builtin_amdgcn_global_load_lds(
      (const __attribute__((address_space(1))) void*)g,
      (__attribute__((address_space(3))) void*)l, 16, 0, 0);
}
__device__ __forceinline__ f32x16 zero16(){
  f32x16 z;
  #pragma unroll
  for (int i = 0; i < 16; ++i) z[i] = 0.f;
  return z;
}
#define mfma32(A, B, C)  __builtin_amdgcn_mfma_f32_32x32x16_bf16((A), (B), (C), 0, 0, 0)
#define mfma8(A, B, C)   __builtin_amdgcn_mfma_f32_32x32x16_fp8_fp8((A), (B), (C), 0, 0, 0)
__device__ __forceinline__ u32t pack4fp8(float a, float b, float c, float d){
  int t = __builtin_amdgcn_cvt_pk_fp8_f32(a, b, 0, false);
  t = __builtin_amdgcn_cvt_pk_fp8_f32(c, d, t, true);
  return (u32t)t;
}
__device__ __forceinline__ unsigned char tofp8(float v){
  return (unsigned char)(__builtin_amdgcn_cvt_pk_fp8_f32(v, 0.f, 0, false) & 0xFF);
}

// ---------------- Kernel W: convert Wq|Wk|Wv f32 -> bf16 into d_out scratch ----
__global__ __launch_bounds__(256) void k_wconv(const float* __restrict__ Wq,
    const float* __restrict__ Wk, const float* __restrict__ Wv,
    u16t* __restrict__ o){
  const int base = (blockIdx.x * 256 + threadIdx.x) * 4;   // 81920 total elems
  float4 v;
  if (base < 8192)        v = *(const float4*)(Wq + base);
  else if (base < 16384)  v = *(const float4*)(Wk + base - 8192);
  else                    v = *(const float4*)(Wv + base - 16384);
  *(uint2*)(o + base) = make_uint2(pk2(v.x, v.y), pk2(v.z, v.w));
}

// ---------------- Kernel 1: fused transpose + projections ----------------
// Q,K bf16 [B][N][32] (Q pre-scaled by log2e). V fp8 e4m3 [B][C][4096] with
// per-row 8B-group swizzle baked in at WRITE time (rule #21).
__global__ __launch_bounds__(256) void k_proj(const float* __restrict__ x,
    const u16t* __restrict__ Wb,
    const float* __restrict__ bq, const float* __restrict__ bk,
    const float* __restrict__ bv,
    u16t* __restrict__ Q, u16t* __restrict__ K, unsigned char* __restrict__ V){
  __shared__ __align__(16) u16t xt[32 * 512];   // 32 chunks x 1KB
  const int b = blockIdx.y, nb = blockIdx.x * 64;
  const int tid = threadIdx.x;
  const int w = tid >> 6, lane = tid & 63;
  const int lo = lane & 15, g = lane >> 4;

  // ---- stage x tile (fragment-order scatter) ----
  const float* xb = x + (size_t)b * CCH * NTOK + nb;
  const int cg = tid >> 4, n0 = (tid & 15) * 4;
  #pragma unroll
  for (int rep = 0; rep < 16; ++rep){
    const int c = rep * 16 + cg;
    float4 v = *(const float4*)(xb + (size_t)c * NTOK + n0);
    const int chunkb = (n0 >> 4) * 8 + (c >> 5);
    const int fl = 16 * ((c >> 3) & 3);
    const int e = c & 7;
    xt[chunkb * 512 + ((n0 & 15) + 0 + fl) * 8 + e] = f2bf(v.x);
    xt[chunkb * 512 + ((n0 & 15) + 1 + fl) * 8 + e] = f2bf(v.y);
    xt[chunkb * 512 + ((n0 & 15) + 2 + fl) * 8 + e] = f2bf(v.z);
    xt[chunkb * 512 + ((n0 & 15) + 3 + fl) * 8 + e] = f2bf(v.w);
  }
  __syncthreads();

  #pragma unroll
  for (int ot = 0; ot < 5; ++ot){
    const u16t* Wrow; const float* bias; int ob; int mode;
    if (ot == 0){
      if (w < 2){ Wrow = Wb;        bias = bq; ob = w * 16;       mode = 0; }
      else      { Wrow = Wb + 8192; bias = bk; ob = (w - 2) * 16; mode = 1; }
    } else { Wrow = Wb + 16384; bias = bv; ob = (ot - 1) * 64 + w * 16; mode = 2; }
    const u16t* wp = Wrow + (size_t)(ob + lo) * CCH + g * 8;

    f32x4 acc[4];
    #pragma unroll
    for (int s = 0; s < 4; ++s) acc[s] = (f32x4){0.f, 0.f, 0.f, 0.f};
    #pragma unroll
    for (int kc = 0; kc < CCH; kc += 32){
      const short8 af = *(const short8*)(wp + kc);
      #pragma unroll
      for (int s = 0; s < 4; ++s){
        const short8 bf = *(const short8*)(xt + (s * 8 + (kc >> 5)) * 512 + lane * 8);
        acc[s] = __builtin_amdgcn_mfma_f32_16x16x32_bf16(af, bf, acc[s], 0, 0, 0);
      }
    }
    #pragma unroll
    for (int s = 0; s < 4; ++s){
      #pragma unroll
      for (int r = 0; r < 4; ++r){
        const int o = ob + 4 * g + r;
        const int n = nb + s * 16 + lo;
        float val = acc[s][r] + bias[o];
        if (mode == 0){
          val *= 1.44269504088896f;
          Q[((size_t)b * NTOK + n) * DQK + o] = f2bf(val);
        } else if (mode == 1){
          K[((size_t)b * NTOK + n) * DQK + o] = f2bf(val);
        } else {
          // fp8 V with baked swizzle: group = (n&63)>>3, slot = group ^ ((o>>1)&7)
          const int swz = ((((s * 2) + (lo >> 3)) ^ ((o >> 1) & 7)) << 3) + (lo & 7);
          V[((size_t)b * CCH + o) * (size_t)NTOK + nb + swz] = tofp8(val);
        }
      }
    }
  }
}

// ---------------- Kernel 2: flash attention + epilogue ----------------
// grid 512, block 1024 (16 waves = 4 q-groups x 4 channel-quarters), 2
// blocks/CU -> 8 waves/SIMD (2x R12's TLP). Wave (qg,cq): PV over 64
// channels (acc = 32 regs). Waves with cq<2 are softmax PRODUCERS for
// j-half = cq (2 mfma32 QK + 16 exp2 + P-pack -> P-LDS dbuf, exactly R12's
// verified address formulas INCLUDING the lane*8 write base -- R14's bug was
// mixing a ql*4 base with lane*8-stride writes, leaving stale fp8-NaN bytes).
// All waves consume all 4 P fragments of their q-group. fp8 PV (mfma8),
// static-m softmax (P=exp2(S) raw), partial-l combined in epilogue.
__global__ __launch_bounds__(1024, 8) void k_attn(
    const u16t* __restrict__ Q, const u16t* __restrict__ K,
    const unsigned char* __restrict__ V,
    const float* __restrict__ x, const float* __restrict__ gamma,
    float* __restrict__ out){
  __shared__ __align__(16) u16t KT[2 * 2048];             // 8 KB K dbuf
  __shared__ __align__(16) unsigned char Vt[2][16384];    // 32 KB V dbuf fp8
  __shared__ __align__(16) unsigned char PT[2][8192];     // 16 KB P dbuf fp8
  const int bid = blockIdx.x;
  const int b  = ((bid & 7) << 1) | ((bid >> 3) & 1);
  const int qt = bid >> 4;
  const int tid = threadIdx.x, w = tid >> 6, lane = tid & 63;
  const int qg = w & 3, cq = w >> 2;          // cq = channel quarter
  const bool prod = (cq < 2);                 // producer for j-half = cq
  const int ql = lane & 31, hi = lane >> 5;
  const int qgb = qt * 128 + qg * 32;

  const u16t* Qb = Q + (size_t)b * NTOK * DQK;
  const u16t* Kb = K + (size_t)b * NTOK * DQK;
  const unsigned char* Vb = V + (size_t)b * CCH * NTOK;

  short8 qf0 = {}, qf1 = {};
  if (prod){
    qf0 = *(const short8*)(Qb + (size_t)(qgb + ql) * DQK + hi * 8);
    qf1 = *(const short8*)(Qb + (size_t)(qgb + ql) * DQK + 16 + hi * 8);
  }

  f32x16 acc[2];                      // 64 channels -> 32 f32
  acc[0] = zero16(); acc[1] = zero16();
  float l = 0.f;

  // ---- precomputed addresses ----
  // V staging: wave stages bytes [w*1024, w*1024+1024): row = w*16+(lane>>2)
  const char* vsrc0 = (const char*)Vb + (size_t)(w * 16 + (lane >> 2)) * NTOK + (lane & 3) * 16;
  // K staging (waves 0..3), fragment order
  const size_t kse = (size_t)((w & 1) * 32 + ql) * DQK + (w >> 1) * 16 + hi * 8;
  const char* ksrc0 = (const char*)Kb + kse * 2;
  const int kla = lane * 16;
  // V A-fragment addr: row c = cq*64 + cs*32 + ql; slot = (kt*2+hi)^((ql>>1)&7)
  // ((c>>1)&7 == (ql>>1)&7 -- cq/cs-invariant)
  int vadd[4];
  #pragma unroll
  for (int kt = 0; kt < 4; ++kt)
    vadd[kt] = (cq * 64 + ql) * 64 + (((kt * 2 + hi) ^ ((ql >> 1) & 7)) << 3);
  const char* ldsV = (const char*)&Vt[0][0];
  const char* ldsK = (const char*)&KT[0];
  const char* ldsP = (const char*)&PT[0][0];
  // producer P write base (R12 VERIFIED formula, ch -> cq): lane*8 stride
  char* ldsPw = (char*)&PT[0][0] + qg * 2048 + cq * 1024 + lane * 8;

  #define ESL(S, B) \
    { S[(B)+0] = __builtin_amdgcn_exp2f(S[(B)+0]); r0 += S[(B)+0]; \
      S[(B)+1] = __builtin_amdgcn_exp2f(S[(B)+1]); r1 += S[(B)+1]; \
      S[(B)+2] = __builtin_amdgcn_exp2f(S[(B)+2]); r2 += S[(B)+2]; \
      S[(B)+3] = __builtin_amdgcn_exp2f(S[(B)+3]); r3 += S[(B)+3]; }

  #define PVCHUNK(CS, VRD, EXPSLICE) \
    { const i64t vf0 = *(const i64t*)(ldsV + vadd[0] + (VRD)*16384 + (CS)*2048); \
      const i64t vf1 = *(const i64t*)(ldsV + vadd[1] + (VRD)*16384 + (CS)*2048); \
      const i64t vf2 = *(const i64t*)(ldsV + vadd[2] + (VRD)*16384 + (CS)*2048); \
      const i64t vf3 = *(const i64t*)(ldsV + vadd[3] + (VRD)*16384 + (CS)*2048); \
      acc[CS] = mfma8(vf0, pb0, acc[CS]); \
      acc[CS] = mfma8(vf1, pb1, acc[CS]); \
      acc[CS] = mfma8(vf2, pb2, acc[CS]); \
      acc[CS] = mfma8(vf3, pb3, acc[CS]); \
      EXPSLICE \
      __builtin_amdgcn_sched_group_barrier(0x100, 4, 0); \
      __builtin_amdgcn_sched_group_barrier(0x8,   4, 0); \
      __builtin_amdgcn_sched_group_barrier(0x2,   8, 0); }

  #define NOSL
  // consumer: all 4 P fragments of own q-group (R12 verified formula)
  #define PBREADS(VRD) \
      const i64t pb0 = *(const i64t*)(ldsP + (VRD)*8192 + qg*2048 + 0*512 + lane*8); \
      const i64t pb1 = *(const i64t*)(ldsP + (VRD)*8192 + qg*2048 + 1*512 + lane*8); \
      const i64t pb2 = *(const i64t*)(ldsP + (VRD)*8192 + qg*2048 + 2*512 + lane*8); \
      const i64t pb3 = *(const i64t*)(ldsP + (VRD)*8192 + qg*2048 + 3*512 + lane*8);

  // QK for j-half = cq from K slot KRD
  #define QKH(KRD, S) \
      { const char* kb_ = ldsK + (KRD)*4096 + cq*1024 + kla; \
        const short8 kfA = *(const short8*)(kb_); \
        const short8 kfB = *(const short8*)(kb_ + 2048); \
        S = mfma32(kfA, qf0, zero16()); \
        S = mfma32(kfB, qf1, S); }

  // pack 16 exp'd scores -> 2 fp8 fragments -> PT[WB] (R12 verified formula)
  #define PWRITE(S, WB) \
      { u32t A1 = pack4fp8(S[0], S[1], S[2],  S[3]); \
        u32t B1 = pack4fp8(S[4], S[5], S[6],  S[7]); \
        lane32swap(A1, B1); \
        u32t A2 = pack4fp8(S[8], S[9], S[10], S[11]); \
        u32t B2 = pack4fp8(S[12], S[13], S[14], S[15]); \
        lane32swap(A2, B2); \
        *(i64t*)(ldsPw + (WB)*8192)       = __builtin_bit_cast(i64t, make_uint2(A1, B1)); \
        *(i64t*)(ldsPw + (WB)*8192 + 512) = __builtin_bit_cast(i64t, make_uint2(A2, B2)); }

  #define ABODY(T, VRD, KRD, KST) { \
      const int toff_ = ((T) + 1) * 64; \
      gload16(vsrc0 + toff_, &Vt[(VRD)^1][w * 1024]); \
      if (w < 4){ const int kt2_ = ((T) + 2 <= 63) ? (T) + 2 : 63; \
        gload16(ksrc0 + (size_t)kt2_ * 4096, &KT[(KST) * 2048 + w * 512]); } \
      PBREADS(VRD) \
      if (prod){ \
        f32x16 s; \
        QKH(KRD, s) \
        float r0 = 0.f, r1 = 0.f, r2 = 0.f, r3 = 0.f; \
        PVCHUNK(0, VRD, ESL(s, 0) ESL(s, 4)) \
        PVCHUNK(1, VRD, ESL(s, 8) ESL(s, 12)) \
        l += (r0 + r1) + (r2 + r3); \
        PWRITE(s, (VRD)^1) \
      } else { \
        PVCHUNK(0, VRD, NOSL) \
        PVCHUNK(1, VRD, NOSL) \
      } \
      __syncthreads(); }

  // prologue: stage V(0)->buf0, K(0)->slot0, K(1)->slot1
  gload16(vsrc0, &Vt[0][w * 1024]);
  if (w < 4){
    gload16(ksrc0,        &KT[0 * 2048 + w * 512]);
    gload16(ksrc0 + 4096, &KT[1 * 2048 + w * 512]);
  }
  __syncthreads();

  // prologue compute: producers emit P(0) -> PT[0]
  if (prod){
    f32x16 s;
    QKH(0, s)
    float r0 = 0.f, r1 = 0.f, r2 = 0.f, r3 = 0.f;
    ESL(s, 0) ESL(s, 4) ESL(s, 8) ESL(s, 12)
    l = (r0 + r1) + (r2 + r3);
    PWRITE(s, 0)
  }
  __syncthreads();   // P(0) visible; K slot0 safe to overwrite in t=0

  for (int t = 0; t < 62; t += 2){
    ABODY(t,     0, 1, 0)
    ABODY(t + 1, 1, 0, 1)
  }
  ABODY(62, 0, 1, 0)

  // tail: PV(63) from Vt[1] / PT[1]
  {
    PBREADS(1)
    PVCHUNK(0, 1, NOSL) PVCHUNK(1, 1, NOSL)
  }

  // ---- epilogue: combine l halves, out = gamma * O/l + x ----
  __syncthreads();                         // all PT[1] reads done
  float* lx = (float*)&PT[0][0];
  if (prod){
    const float lhalf = swapadd(l);        // full sum over j-half = cq
    if (lane < 32) lx[(qg * 2 + cq) * 32 + ql] = lhalf;
  }
  __syncthreads();
  const float lfull = lx[(qg * 2 + 0) * 32 + ql] + lx[(qg * 2 + 1) * 32 + ql];
  const float inv = 1.0f / lfull;
  const float gm = gamma[0];
  const int n = qgb + ql;
  #pragma unroll
  for (int cs = 0; cs < 2; ++cs){
    #pragma unroll
    for (int r = 0; r < 16; ++r){
      const int c = cq * 64 + cs * 32 + (r & 3) + 8 * (r >> 2) + 4 * hi;
      const size_t idx = ((size_t)b * CCH + c) * NTOK + n;
      out[idx] = gm * (acc[cs][r] * inv) + x[idx];
    }
  }
  #undef ESL
  #undef PVCHUNK
  #undef NOSL
  #undef PBREADS
  #undef QKH
  #undef PWRITE
  #undef ABODY
}

extern "C" void kernel_launch(void* const* d_in, const int* in_sizes, int n_in,
                              void* d_out, int out_size, void* d_ws, size_t ws_size,
                              hipStream_t stream) {
  const float* x     = (const float*)d_in[0];
  const float* Wq    = (const float*)d_in[1];
  const float* bq    = (const float*)d_in[2];
  const float* Wk    = (const float*)d_in[3];
  const float* bk    = (const float*)d_in[4];
  const float* Wv    = (const float*)d_in[5];
  const float* bv    = (const float*)d_in[6];
  const float* gamma = (const float*)d_in[7];
  float* out = (float*)d_out;

  char* ws = (char*)d_ws;
  u16t* Qw = (u16t*)(ws);                      //  4 MB
  u16t* Kw = (u16t*)(ws + 4194304);            //  4 MB
  unsigned char* Vw = (unsigned char*)(ws + 8388608);  // 16 MB fp8
  u16t* Wbf = (u16t*)d_out;                    // 160 KB scratch, overwritten by k_attn

  hipLaunchKernelGGL(k_wconv, dim3(80), dim3(256), 0, stream, Wq, Wk, Wv, Wbf);
  hipLaunchKernelGGL(k_proj, dim3(NTOK / 64, BB), dim3(256), 0, stream,
                     x, Wbf, bq, bk, bv, Qw, Kw, Vw);
  hipLaunchKernelGGL(k_attn, dim3(512), dim3(1024), 0, stream,
                     Qw, Kw, Vw, x, gamma, out);
}

// Round 16
// 163.207 us; speedup vs baseline: 3.5526x; 2.5319x over previous
//
#include <hip/hip_runtime.h>
#include <hip/hip_bf16.h>

#define BB   16
#define CCH  256
#define DQK  32
#define NTOK 4096

typedef __attribute__((ext_vector_type(8)))  short short8;
typedef __attribute__((ext_vector_type(4)))  float f32x4;
typedef __attribute__((ext_vector_type(16))) float f32x16;
typedef unsigned short u16t;
typedef unsigned int   u32t;
typedef long long      i64t;

__device__ __forceinline__ u16t f2bf(float f){
  u32t u = __builtin_bit_cast(u32t, f);
  u += 0x7FFFu + ((u >> 16) & 1u);
  return (u16t)(u >> 16);
}
__device__ __forceinline__ u32t pk2(float a, float b){
  return (u32t)f2bf(a) | ((u32t)f2bf(b) << 16);
}
__device__ __forceinline__ void lane32swap(u32t& a, u32t& b){
  asm("v_permlane32_swap_b32 %0, %1" : "+v"(a), "+v"(b));
}
__device__ __forceinline__ float swapadd(float x){
  u32t a = __builtin_bit_cast(u32t, x), b = a;
  lane32swap(a, b);
  return __builtin_bit_cast(float, a) + __builtin_bit_cast(float, b);
}
__device__ __forceinline__ void gload16(const void* g, void* l){
  __builtin_amdgcn_global_load_lds(
      (const __attribute__((address_space(1))) void*)g,
      (__attribute__((address_space(3))) void*)l, 16, 0, 0);
}
__device__ __forceinline__ f32x16 zero16(){
  f32x16 z;
  #pragma unroll
  for (int i = 0; i < 16; ++i) z[i] = 0.f;
  return z;
}
#define mfma32(A, B, C)  __builtin_amdgcn_mfma_f32_32x32x16_bf16((A), (B), (C), 0, 0, 0)
#define mfma8(A, B, C)   __builtin_amdgcn_mfma_f32_32x32x16_fp8_fp8((A), (B), (C), 0, 0, 0)
__device__ __forceinline__ u32t pack4fp8(float a, float b, float c, float d){
  int t = __builtin_amdgcn_cvt_pk_fp8_f32(a, b, 0, false);
  t = __builtin_amdgcn_cvt_pk_fp8_f32(c, d, t, true);
  return (u32t)t;
}
__device__ __forceinline__ unsigned char tofp8(float v){
  return (unsigned char)(__builtin_amdgcn_cvt_pk_fp8_f32(v, 0.f, 0, false) & 0xFF);
}

// ---------------- Kernel W: convert Wq|Wk|Wv f32 -> bf16 into d_out scratch ----
__global__ __launch_bounds__(256) void k_wconv(const float* __restrict__ Wq,
    const float* __restrict__ Wk, const float* __restrict__ Wv,
    u16t* __restrict__ o){
  const int base = (blockIdx.x * 256 + threadIdx.x) * 4;   // 81920 total elems
  float4 v;
  if (base < 8192)        v = *(const float4*)(Wq + base);
  else if (base < 16384)  v = *(const float4*)(Wk + base - 8192);
  else                    v = *(const float4*)(Wv + base - 16384);
  *(uint2*)(o + base) = make_uint2(pk2(v.x, v.y), pk2(v.z, v.w));
}

// ---------------- Kernel 1: fused transpose + projections ----------------
// Q,K bf16 [B][N][32] (Q pre-scaled by log2e). V fp8 e4m3 [B][C][4096] with
// per-row 8B-group swizzle baked in at WRITE time (rule #21).
__global__ __launch_bounds__(256) void k_proj(const float* __restrict__ x,
    const u16t* __restrict__ Wb,
    const float* __restrict__ bq, const float* __restrict__ bk,
    const float* __restrict__ bv,
    u16t* __restrict__ Q, u16t* __restrict__ K, unsigned char* __restrict__ V){
  __shared__ __align__(16) u16t xt[32 * 512];   // 32 chunks x 1KB
  const int b = blockIdx.y, nb = blockIdx.x * 64;
  const int tid = threadIdx.x;
  const int w = tid >> 6, lane = tid & 63;
  const int lo = lane & 15, g = lane >> 4;

  // ---- stage x tile (fragment-order scatter) ----
  const float* xb = x + (size_t)b * CCH * NTOK + nb;
  const int cg = tid >> 4, n0 = (tid & 15) * 4;
  #pragma unroll
  for (int rep = 0; rep < 16; ++rep){
    const int c = rep * 16 + cg;
    float4 v = *(const float4*)(xb + (size_t)c * NTOK + n0);
    const int chunkb = (n0 >> 4) * 8 + (c >> 5);
    const int fl = 16 * ((c >> 3) & 3);
    const int e = c & 7;
    xt[chunkb * 512 + ((n0 & 15) + 0 + fl) * 8 + e] = f2bf(v.x);
    xt[chunkb * 512 + ((n0 & 15) + 1 + fl) * 8 + e] = f2bf(v.y);
    xt[chunkb * 512 + ((n0 & 15) + 2 + fl) * 8 + e] = f2bf(v.z);
    xt[chunkb * 512 + ((n0 & 15) + 3 + fl) * 8 + e] = f2bf(v.w);
  }
  __syncthreads();

  #pragma unroll
  for (int ot = 0; ot < 5; ++ot){
    const u16t* Wrow; const float* bias; int ob; int mode;
    if (ot == 0){
      if (w < 2){ Wrow = Wb;        bias = bq; ob = w * 16;       mode = 0; }
      else      { Wrow = Wb + 8192; bias = bk; ob = (w - 2) * 16; mode = 1; }
    } else { Wrow = Wb + 16384; bias = bv; ob = (ot - 1) * 64 + w * 16; mode = 2; }
    const u16t* wp = Wrow + (size_t)(ob + lo) * CCH + g * 8;

    f32x4 acc[4];
    #pragma unroll
    for (int s = 0; s < 4; ++s) acc[s] = (f32x4){0.f, 0.f, 0.f, 0.f};
    #pragma unroll
    for (int kc = 0; kc < CCH; kc += 32){
      const short8 af = *(const short8*)(wp + kc);
      #pragma unroll
      for (int s = 0; s < 4; ++s){
        const short8 bf = *(const short8*)(xt + (s * 8 + (kc >> 5)) * 512 + lane * 8);
        acc[s] = __builtin_amdgcn_mfma_f32_16x16x32_bf16(af, bf, acc[s], 0, 0, 0);
      }
    }
    #pragma unroll
    for (int s = 0; s < 4; ++s){
      #pragma unroll
      for (int r = 0; r < 4; ++r){
        const int o = ob + 4 * g + r;
        const int n = nb + s * 16 + lo;
        float val = acc[s][r] + bias[o];
        if (mode == 0){
          val *= 1.44269504088896f;
          Q[((size_t)b * NTOK + n) * DQK + o] = f2bf(val);
        } else if (mode == 1){
          K[((size_t)b * NTOK + n) * DQK + o] = f2bf(val);
        } else {
          // fp8 V with baked swizzle: group = (n&63)>>3, slot = group ^ ((o>>1)&7)
          const int swz = ((((s * 2) + (lo >> 3)) ^ ((o >> 1) & 7)) << 3) + (lo & 7);
          V[((size_t)b * CCH + o) * (size_t)NTOK + nb + swz] = tofp8(val);
        }
      }
    }
  }
}

// ---------------- Kernel 2: flash attention + epilogue ----------------
// grid 512, block 512 (8 waves = 4 q-groups x 2 ch-halves), 2 blocks/CU ->
// 4 waves/SIMD (register-pool max: 16 waves/CU x 128 unified regs).
// P-SHARING: wave (qg,ch) computes softmax only for j-half=ch (2 mfma32,
// 16 exp2, packs kt {2ch,2ch+1} -> P-LDS dbuf); after the per-iter barrier
// every wave reads all 4 kt of its q-group for PV over its 128 channels.
// fp8 PV (mfma8), static-m softmax (P=exp2(S) raw, scale cancels in O/l),
// SGB-interleaved PV||EXP, partial-l halves combined once in epilogue.
__global__ __launch_bounds__(512, 4) void k_attn(
    const u16t* __restrict__ Q, const u16t* __restrict__ K,
    const unsigned char* __restrict__ V,
    const float* __restrict__ x, const float* __restrict__ gamma,
    float* __restrict__ out){
  __shared__ __align__(16) u16t KT[2 * 2048];             // 8 KB K dbuf
  __shared__ __align__(16) unsigned char Vt[2][16384];    // 32 KB V dbuf fp8
  __shared__ __align__(16) unsigned char PT[2][8192];     // 16 KB P dbuf fp8
  const int bid = blockIdx.x;
  const int b  = ((bid & 7) << 1) | ((bid >> 3) & 1);
  const int qt = bid >> 4;
  const int tid = threadIdx.x, w = tid >> 6, lane = tid & 63;
  const int qg = w & 3, ch = w >> 2;
  const int ql = lane & 31, hi = lane >> 5;
  const int qgb = qt * 128 + qg * 32;

  const u16t* Qb = Q + (size_t)b * NTOK * DQK;
  const u16t* Kb = K + (size_t)b * NTOK * DQK;
  const unsigned char* Vb = V + (size_t)b * CCH * NTOK;

  const short8 qf0 = *(const short8*)(Qb + (size_t)(qgb + ql) * DQK + hi * 8);
  const short8 qf1 = *(const short8*)(Qb + (size_t)(qgb + ql) * DQK + 16 + hi * 8);

  f32x16 acc[4];                      // 128 channels -> 64 f32
  #pragma unroll
  for (int c = 0; c < 4; ++c) acc[c] = zero16();
  float l = 0.f;

  // ---- precomputed addresses ----
  // V staging: wave stages bytes [w*2048, w*2048+2048): row = a>>6, col16 = lane&3
  const char* vsrc0 = (const char*)Vb + (size_t)(w * 32 + (lane >> 2)) * NTOK + (lane & 3) * 16;
  // K staging (waves 0..3), fragment order: frag f: j-half = f&1, d-half = f>>1
  const size_t kse = (size_t)((w & 1) * 32 + ql) * DQK + (w >> 1) * 16 + hi * 8;
  const char* ksrc0 = (const char*)Kb + kse * 2;
  const int kla = lane * 16;
  int vadd[4];                        // byte addr of 8B V fragment, row = ch*128+ql
  #pragma unroll
  for (int kt = 0; kt < 4; ++kt)
    vadd[kt] = (ch * 128 + ql) * 64 + (((kt * 2 + hi) ^ ((ql >> 1) & 7)) << 3);
  const char* ldsV = (const char*)&Vt[0][0];
  const char* ldsK = (const char*)&KT[0];
  const char* ldsP = (const char*)&PT[0][0];
  char* ldsPw = (char*)&PT[0][0] + qg * 2048 + ch * 1024 + lane * 8;

  #define ESL(S, B) \
    { S[(B)+0] = __builtin_amdgcn_exp2f(S[(B)+0]); r0 += S[(B)+0]; \
      S[(B)+1] = __builtin_amdgcn_exp2f(S[(B)+1]); r1 += S[(B)+1]; \
      S[(B)+2] = __builtin_amdgcn_exp2f(S[(B)+2]); r2 += S[(B)+2]; \
      S[(B)+3] = __builtin_amdgcn_exp2f(S[(B)+3]); r3 += S[(B)+3]; }

  #define PVCHUNK(CS, VRD, EXPSLICE) \
    { const i64t vf0 = *(const i64t*)(ldsV + vadd[0] + (VRD)*16384 + (CS)*2048); \
      const i64t vf1 = *(const i64t*)(ldsV + vadd[1] + (VRD)*16384 + (CS)*2048); \
      const i64t vf2 = *(const i64t*)(ldsV + vadd[2] + (VRD)*16384 + (CS)*2048); \
      const i64t vf3 = *(const i64t*)(ldsV + vadd[3] + (VRD)*16384 + (CS)*2048); \
      acc[CS] = mfma8(vf0, pb0, acc[CS]); \
      acc[CS] = mfma8(vf1, pb1, acc[CS]); \
      acc[CS] = mfma8(vf2, pb2, acc[CS]); \
      acc[CS] = mfma8(vf3, pb3, acc[CS]); \
      EXPSLICE \
      __builtin_amdgcn_sched_group_barrier(0x100, 4, 0); \
      __builtin_amdgcn_sched_group_barrier(0x8,   4, 0); \
      __builtin_amdgcn_sched_group_barrier(0x2,   8, 0); }

  #define NOSL
  // read P(t) fragments (all 4 kt of own q-group) from PT[VRD]
  #define PBREADS(VRD) \
      const i64t pb0 = *(const i64t*)(ldsP + (VRD)*8192 + qg*2048 + 0*512 + lane*8); \
      const i64t pb1 = *(const i64t*)(ldsP + (VRD)*8192 + qg*2048 + 1*512 + lane*8); \
      const i64t pb2 = *(const i64t*)(ldsP + (VRD)*8192 + qg*2048 + 2*512 + lane*8); \
      const i64t pb3 = *(const i64t*)(ldsP + (VRD)*8192 + qg*2048 + 3*512 + lane*8);

  // QK for own j-half from K slot KRD; s = 16 f32 (j-local rows x 32 q)
  #define QKH(KRD, S) \
      { const char* kb_ = ldsK + (KRD)*4096 + ch*1024 + kla; \
        const short8 kfA = *(const short8*)(kb_); \
        const short8 kfB = *(const short8*)(kb_ + 2048); \
        S = mfma32(kfA, qf0, zero16()); \
        S = mfma32(kfB, qf1, S); }

  // pack 16 exp'd scores -> 2 fp8 fragments -> PT[WB]
  #define PWRITE(S, WB) \
      { u32t A1 = pack4fp8(S[0], S[1], S[2],  S[3]); \
        u32t B1 = pack4fp8(S[4], S[5], S[6],  S[7]); \
        lane32swap(A1, B1); \
        u32t A2 = pack4fp8(S[8], S[9], S[10], S[11]); \
        u32t B2 = pack4fp8(S[12], S[13], S[14], S[15]); \
        lane32swap(A2, B2); \
        *(i64t*)(ldsPw + (WB)*8192)       = __builtin_bit_cast(i64t, make_uint2(A1, B1)); \
        *(i64t*)(ldsPw + (WB)*8192 + 512) = __builtin_bit_cast(i64t, make_uint2(A2, B2)); }

  #define ABODY(T, VRD, KRD, KST) { \
      const int toff_ = ((T) + 1) * 64; \
      gload16(vsrc0 + toff_,                     &Vt[(VRD)^1][w * 2048]); \
      gload16(vsrc0 + (size_t)16 * NTOK + toff_, &Vt[(VRD)^1][w * 2048 + 1024]); \
      if (w < 4){ const int kt2_ = ((T) + 2 <= 63) ? (T) + 2 : 63; \
        gload16(ksrc0 + (size_t)kt2_ * 4096, &KT[(KST) * 2048 + w * 512]); } \
      PBREADS(VRD) \
      f32x16 s; \
      QKH(KRD, s) \
      float r0 = 0.f, r1 = 0.f, r2 = 0.f, r3 = 0.f; \
      PVCHUNK(0, VRD, ESL(s, 0)) \
      PVCHUNK(1, VRD, ESL(s, 4)) \
      PVCHUNK(2, VRD, ESL(s, 8)) \
      PVCHUNK(3, VRD, ESL(s, 12)) \
      l += (r0 + r1) + (r2 + r3); \
      PWRITE(s, (VRD)^1) \
      __syncthreads(); }

  // prologue: stage V(0)->buf0, K(0)->slot0, K(1)->slot1
  gload16(vsrc0,                     &Vt[0][w * 2048]);
  gload16(vsrc0 + (size_t)16 * NTOK, &Vt[0][w * 2048 + 1024]);
  if (w < 4){
    gload16(ksrc0,        &KT[0 * 2048 + w * 512]);
    gload16(ksrc0 + 4096, &KT[1 * 2048 + w * 512]);
  }
  __syncthreads();

  // prologue compute: P(0) for own j-half -> PT[0]
  {
    f32x16 s;
    QKH(0, s)
    float r0 = 0.f, r1 = 0.f, r2 = 0.f, r3 = 0.f;
    ESL(s, 0) ESL(s, 4) ESL(s, 8) ESL(s, 12)
    l = (r0 + r1) + (r2 + r3);
    PWRITE(s, 0)
  }
  __syncthreads();   // P(0) visible; K slot0 safe to overwrite in t=0

  for (int t = 0; t < 62; t += 2){
    ABODY(t,     0, 1, 0)
    ABODY(t + 1, 1, 0, 1)
  }
  ABODY(62, 0, 1, 0)

  // tail: PV(63) from Vt[1] / PT[1]
  {
    PBREADS(1)
    PVCHUNK(0, 1, NOSL) PVCHUNK(1, 1, NOSL)
    PVCHUNK(2, 1, NOSL) PVCHUNK(3, 1, NOSL)
  }

  // ---- epilogue: combine l halves, out = gamma * O/l + x ----
  __syncthreads();                         // all PT[1] reads done
  const float lhalf = swapadd(l);          // full sum over own j-half
  float* lx = (float*)&PT[0][0];
  if (lane < 32) lx[(qg * 2 + ch) * 32 + ql] = lhalf;
  __syncthreads();
  const float lfull = lhalf + lx[(qg * 2 + (ch ^ 1)) * 32 + ql];
  const float inv = 1.0f / lfull;
  const float gm = gamma[0];
  const int n = qgb + ql;
  #pragma unroll
  for (int cs = 0; cs < 4; ++cs){
    #pragma unroll
    for (int r = 0; r < 16; ++r){
      const int c = ch * 128 + cs * 32 + (r & 3) + 8 * (r >> 2) + 4 * hi;
      const size_t idx = ((size_t)b * CCH + c) * NTOK + n;
      out[idx] = gm * (acc[cs][r] * inv) + x[idx];
    }
  }
  #undef ESL
  #undef PVCHUNK
  #undef NOSL
  #undef PBREADS
  #undef QKH
  #undef PWRITE
  #undef ABODY
}

extern "C" void kernel_launch(void* const* d_in, const int* in_sizes, int n_in,
                              void* d_out, int out_size, void* d_ws, size_t ws_size,
                              hipStream_t stream) {
  const float* x     = (const float*)d_in[0];
  const float* Wq    = (const float*)d_in[1];
  const float* bq    = (const float*)d_in[2];
  const float* Wk    = (const float*)d_in[3];
  const float* bk    = (const float*)d_in[4];
  const float* Wv    = (const float*)d_in[5];
  const float* bv    = (const float*)d_in[6];
  const float* gamma = (const float*)d_in[7];
  float* out = (float*)d_out;

  char* ws = (char*)d_ws;
  u16t* Qw = (u16t*)(ws);                      //  4 MB
  u16t* Kw = (u16t*)(ws + 4194304);            //  4 MB
  unsigned char* Vw = (unsigned char*)(ws + 8388608);  // 16 MB fp8
  u16t* Wbf = (u16t*)d_out;                    // 160 KB scratch, overwritten by k_attn

  hipLaunchKernelGGL(k_wconv, dim3(80), dim3(256), 0, stream, Wq, Wk, Wv, Wbf);
  hipLaunchKernelGGL(k_proj, dim3(NTOK / 64, BB), dim3(256), 0, stream,
                     x, Wbf, bq, bk, bv, Qw, Kw, Vw);
  hipLaunchKernelGGL(k_attn, dim3(512), dim3(512), 0, stream,
                     Qw, Kw, Vw, x, gamma, out);
}